// Round 15
// baseline (186.886 us; speedup 1.0000x reference)
//
#include <hip/hip_runtime.h>
#include <math.h>

#define N_NODES 50000
#define N_EDGES 800000
#define C 128
#define OUTC 64
#define CAP 64               // padded-CSR slots/node; P(deg>64) ~ 3e-20/node
#define NSLICE 8             // XCD count; dst-slice per block-group (blk&7)
#define SLICE_N 6250         // 50000 / 8 exactly

#define FILL_CH 3125         // edge chunks: 800000 / 256 exactly
#define FILLG_B (FILL_CH * NSLICE)   // 25000 fill blocks (8 groups)
#define CAST_B 3125          // 50000*128/8 / 256 exactly
#define PREPW_B 128          // per layer, 3 layers
#define WLIN_B 32            // 128*64/256

#define BN 32                // nodes per fused block (32 rows, 8 waves)

typedef __attribute__((ext_vector_type(8))) short bfrag;   // 8 bf16 (4 VGPRs)
typedef __attribute__((ext_vector_type(4))) float ffrag;   // 4 fp32 acc
typedef __attribute__((ext_vector_type(2))) float f32x2;
typedef __attribute__((ext_vector_type(4))) float f32x4;
typedef __attribute__((ext_vector_type(4))) uint u32x4;
typedef __attribute__((ext_vector_type(2))) uint u32x2;

__device__ __forceinline__ ushort f2bf(float f) {
    uint u = __builtin_bit_cast(uint, f);
    uint r = (u + 0x7FFFu + ((u >> 16) & 1u)) >> 16;       // RNE
    return (ushort)r;
}
__device__ __forceinline__ float bflo(uint v) {            // low bf16 of packed pair
    uint u = v << 16; return __builtin_bit_cast(float, u);
}
__device__ __forceinline__ float bfhi(uint v) {            // high bf16
    uint u = v & 0xFFFF0000u; return __builtin_bit_cast(float, u);
}
// fp8 e4m3 (HW-native, gfx950 OCP): pack 4 f32 -> 4 fp8 bytes in a uint
__device__ __forceinline__ uint pkfp8x4(float a, float b, float c, float d) {
    int w = __builtin_amdgcn_cvt_pk_fp8_f32(a, b, 0, false);
    w = __builtin_amdgcn_cvt_pk_fp8_f32(c, d, w, true);
    return (uint)w;
}
__device__ __forceinline__ uchar pkfp8(float v) {
    return (uchar)(__builtin_amdgcn_cvt_pk_fp8_f32(v, v, 0, false) & 0xFF);
}

// ---------------------------------------------------------------------------
// Mega prep kernel. NEW r15: all stream-once traffic (x/dst/src loads, xb/xq
// stores) is NON-TEMPORAL so it can't evict the fill's L2-resident slot lines
// — r14 showed 23 MB of slot write-amplification caused by the co-running
// cast streams polluting the same per-XCD L2s.
// ---------------------------------------------------------------------------

__global__ __launch_bounds__(256) void k_prep_mega(
    const int* __restrict__ src, const int* __restrict__ dst,
    int* __restrict__ cnt, ushort* __restrict__ slots,
    const float* __restrict__ x, uint* __restrict__ xb,
    uint* __restrict__ xq,
    const float* __restrict__ Wl0, const float* __restrict__ Wr0,
    const float* __restrict__ Wl1, const float* __restrict__ Wr1,
    const float* __restrict__ Wl2, const float* __restrict__ Wr2,
    const float* __restrict__ Wlin,
    ushort* __restrict__ wp, ushort* __restrict__ wpl) {
    int blk = blockIdx.x;
    if (blk < FILLG_B) {
        int grp = blk & 7;                             // target dst slice / XCD
        int e = (blk >> 3) * 256 + threadIdx.x;        // < 800000 exactly
        int d = __builtin_nontemporal_load(&dst[e]);
        if ((unsigned)(d - grp * SLICE_N) < (unsigned)SLICE_N) {
            int s = __builtin_nontemporal_load(&src[e]);
            int pos = atomicAdd(&cnt[d], 1);
            if (pos < CAP) slots[d * CAP + pos] = (ushort)s;
        }
    } else if (blk < FILLG_B + CAST_B) {
        int i = (blk - FILLG_B) * 256 + threadIdx.x;   // < 800000 exactly
        const f32x4* xv = (const f32x4*)x;
        f32x4 a = __builtin_nontemporal_load(&xv[i * 2]);
        f32x4 b = __builtin_nontemporal_load(&xv[i * 2 + 1]);
        u32x4 o;
        o.x = (uint)f2bf(a.x) | ((uint)f2bf(a.y) << 16);
        o.y = (uint)f2bf(a.z) | ((uint)f2bf(a.w) << 16);
        o.z = (uint)f2bf(b.x) | ((uint)f2bf(b.y) << 16);
        o.w = (uint)f2bf(b.z) | ((uint)f2bf(b.w) << 16);
        __builtin_nontemporal_store(o, &((u32x4*)xb)[i]);
        u32x2 q;
        q.x = pkfp8x4(a.x, a.y, a.z, a.w);
        q.y = pkfp8x4(b.x, b.y, b.z, b.w);
        __builtin_nontemporal_store(q, &((u32x2*)xq)[i]);
    } else if (blk < FILLG_B + CAST_B + 3 * PREPW_B) {
        int sub = blk - (FILLG_B + CAST_B);
        int layer = sub >> 7;                          // /128
        const float *Wl, *Wr;
        if (layer == 0)      { Wl = Wl0; Wr = Wr0; }
        else if (layer == 1) { Wl = Wl1; Wr = Wr1; }
        else                 { Wl = Wl2; Wr = Wr2; }
        // wp[((nf*8 + ks)*64 + lane)*8 + j] = Wcat[k][n],
        //   n = nf*16 + (lane&15), k = ks*32 + (lane>>4)*8 + j
        int idx = (sub & 127) * 256 + threadIdx.x;     // 0..32767
        int j = idx & 7;
        int lane = (idx >> 3) & 63;
        int ks = (idx >> 9) & 7;
        int nf = idx >> 12;
        int n = nf * 16 + (lane & 15);
        int k = ks * 32 + (lane >> 4) * 8 + j;
        float v = (k < C) ? Wl[k * C + n] : Wr[(k - C) * C + n];
        wp[layer * 32768 + idx] = f2bf(v);
    } else {
        // Wlin pack: K=128 (4 ks), N=64 (4 nf); idx == ((nf*4+ks)*64+lane)*8+j
        int idx = (blk - (FILLG_B + CAST_B + 3 * PREPW_B)) * 256 + threadIdx.x;
        int j = idx & 7;
        int lane = (idx >> 3) & 63;
        int ks = (idx >> 9) & 3;
        int nf = idx >> 11;                            // 0..3
        int n = nf * 16 + (lane & 15);
        int k = ks * 32 + (lane >> 4) * 8 + j;
        wpl[idx] = f2bf(Wlin[k * OUTC + n]);
    }
}

// ---------------------------------------------------------------------------
// Gather stage (fp8 table, r14-proven). NT on the hv residual read (stream-
// once per XCD) so it can't evict reusable fp8-table lines; hq/slots reads
// stay cached (each table line has ~2x reuse per XCD per layer).
// ---------------------------------------------------------------------------

#define ACCQ(P, W, V) {                                                       \
    f32x2 p01 = __builtin_amdgcn_cvt_pk_f32_fp8((int)V.x, false);             \
    f32x2 p23 = __builtin_amdgcn_cvt_pk_f32_fp8((int)V.x, true);              \
    f32x2 p45 = __builtin_amdgcn_cvt_pk_f32_fp8((int)V.y, false);             \
    f32x2 p67 = __builtin_amdgcn_cvt_pk_f32_fp8((int)V.y, true);              \
    P##0 = fmaf(W, p01[0], P##0); P##1 = fmaf(W, p01[1], P##1);               \
    P##2 = fmaf(W, p23[0], P##2); P##3 = fmaf(W, p23[1], P##3);               \
    P##4 = fmaf(W, p45[0], P##4); P##5 = fmaf(W, p45[1], P##5);               \
    P##6 = fmaf(W, p67[0], P##6); P##7 = fmaf(W, p67[1], P##7); }

__device__ __forceinline__ void sage_gather_stage(
    ushort* A, const uint* __restrict__ hb, const u32x2* __restrict__ hq,
    const int* __restrict__ cnt, const ushort* __restrict__ slots,
    int node0, int w, int lane) {
    const int grp = lane >> 4;
    const int slot = lane & 15;
    for (int rr = 0; rr < 4; ++rr) {
        int r = (w << 2) | rr;
        int node = node0 + r;
        int n = 0;
        u32x4 hv = (u32x4)0u;
        if (node < N_NODES) {
            n = cnt[node];
            n = (n > CAP) ? CAP : n;
            if (grp == 0)
                hv = __builtin_nontemporal_load(
                    (const u32x4*)&hb[node * 64 + slot * 4]);
        }
        float s0 = 0, s1 = 0, s2 = 0, s3 = 0, s4 = 0, s5 = 0, s6 = 0, s7 = 0;
        if (n > 0) {
            int sv = slots[node * CAP + ((lane < n) ? lane : 0)];
            for (int k = 0; k < n; k += 16) {
                int w0 = k + grp, w1 = k + 4 + grp;
                int w2 = k + 8 + grp, w3 = k + 12 + grp;
                int sA = __shfl(sv, w0), sB = __shfl(sv, w1);
                int sC = __shfl(sv, w2), sD = __shfl(sv, w3);
                float fA = (w0 < n) ? 1.f : 0.f;
                float fB = (w1 < n) ? 1.f : 0.f;
                float fC = (w2 < n) ? 1.f : 0.f;
                float fD = (w3 < n) ? 1.f : 0.f;
                // 4 independent 8B gathers in flight (fp8 row = 16 uint2)
                u32x2 a = hq[sA * 16 + slot];
                u32x2 b = hq[sB * 16 + slot];
                u32x2 c = hq[sC * 16 + slot];
                u32x2 d = hq[sD * 16 + slot];
                ACCQ(s, fA, a); ACCQ(s, fB, b);
                ACCQ(s, fC, c); ACCQ(s, fD, d);
            }
        }
#pragma unroll
        for (int o = 16; o <= 32; o <<= 1) {
            s0 += __shfl_xor(s0, o); s1 += __shfl_xor(s1, o);
            s2 += __shfl_xor(s2, o); s3 += __shfl_xor(s3, o);
            s4 += __shfl_xor(s4, o); s5 += __shfl_xor(s5, o);
            s6 += __shfl_xor(s6, o); s7 += __shfl_xor(s7, o);
        }
        if (grp == 0) {
            float rd = (n > 0) ? 1.0f / (float)n : 0.f;
            u32x4 o4;
            o4.x = (uint)f2bf(s0 * rd) | ((uint)f2bf(s1 * rd) << 16);
            o4.y = (uint)f2bf(s2 * rd) | ((uint)f2bf(s3 * rd) << 16);
            o4.z = (uint)f2bf(s4 * rd) | ((uint)f2bf(s5 * rd) << 16);
            o4.w = (uint)f2bf(s6 * rd) | ((uint)f2bf(s7 * rd) << 16);
            // mean -> chunk slot; h -> chunk 16+slot (XOR row swizzle)
            *(u32x4*)&A[r * 256 + (slot ^ (r & 7)) * 8] = o4;
            *(u32x4*)&A[r * 256 + ((16 + slot) ^ (r & 7)) * 8] = hv;
        }
    }
}

// ---------------------------------------------------------------------------
// Fused SAGE layer: 512 threads = 8 waves, 32 nodes, 4 blocks/CU (r13).
// Epilogue dual-writes h bf16 + fp8 with NT stores (consumed next launch,
// mostly cross-XCD -> keep out of this XCD's L2).
// ---------------------------------------------------------------------------

__global__ __launch_bounds__(512, 8) void k_sage_f(
    const uint* __restrict__ hb, const u32x2* __restrict__ hq,
    const int* __restrict__ cnt, const ushort* __restrict__ slots,
    const ushort* __restrict__ Wp, const float* __restrict__ bl,
    ushort* __restrict__ out_b, uchar* __restrict__ out_q) {
    __shared__ __align__(16) ushort A[BN * 256];
    const int t = threadIdx.x;
    const int w = t >> 6, lane = t & 63;
    const int node0 = blockIdx.x * BN;

    sage_gather_stage(A, hb, hq, cnt, slots, node0, w, lane);
    __syncthreads();

    const int wm = w >> 2, wn = w & 3;
    const int lg = lane >> 4, lr = lane & 15;
    ffrag acc[2];
    acc[0] = (ffrag)0.f;
    acc[1] = (ffrag)0.f;
#pragma unroll 2
    for (int ks = 0; ks < 8; ++ks) {
        int r = wm * 16 + lr;
        int c = ks * 4 + lg;
        bfrag a = *(const bfrag*)&A[r * 256 + (c ^ (r & 7)) * 8];
#pragma unroll
        for (int in = 0; in < 2; ++in) {
            int nf = wn * 2 + in;
            bfrag b = *(const bfrag*)&Wp[(((nf * 8) + ks) * 64 + lane) * 8];
            acc[in] = __builtin_amdgcn_mfma_f32_16x16x32_bf16(a, b, acc[in],
                                                              0, 0, 0);
        }
    }
#pragma unroll
    for (int in = 0; in < 2; ++in) {
        int ch = (wn * 2 + in) * 16 + lr;
        float bias = bl[ch];
#pragma unroll
        for (int rq = 0; rq < 4; ++rq) {
            int node = node0 + wm * 16 + lg * 4 + rq;
            if (node < N_NODES) {
                float v = acc[in][rq] + bias;
                v = (v > 0.f) ? v : 0.f;
                __builtin_nontemporal_store(f2bf(v), &out_b[node * C + ch]);
                __builtin_nontemporal_store(pkfp8(v), &out_q[node * C + ch]);
            }
        }
    }
}

// ---------------------------------------------------------------------------
// Fused last layer: gather + GEMM + final projection + log_softmax.
// Second GEMM + softmax on waves 0-1 (rows w*16..+15 each). No h output.
// ---------------------------------------------------------------------------

__global__ __launch_bounds__(512, 8) void k_sage_fout(
    const uint* __restrict__ hb, const u32x2* __restrict__ hq,
    const int* __restrict__ cnt, const ushort* __restrict__ slots,
    const ushort* __restrict__ Wp, const float* __restrict__ bl,
    const ushort* __restrict__ Wpl, const float* __restrict__ blin,
    float* __restrict__ out) {
    __shared__ __align__(16) ushort A[BN * 256];
    const int t = threadIdx.x;
    const int w = t >> 6, lane = t & 63;
    const int node0 = blockIdx.x * BN;

    sage_gather_stage(A, hb, hq, cnt, slots, node0, w, lane);
    __syncthreads();

    const int wm = w >> 2, wn = w & 3;
    const int lg = lane >> 4, lr = lane & 15;
    ffrag acc[2];
    acc[0] = (ffrag)0.f;
    acc[1] = (ffrag)0.f;
#pragma unroll 2
    for (int ks = 0; ks < 8; ++ks) {
        int r = wm * 16 + lr;
        int c = ks * 4 + lg;
        bfrag a = *(const bfrag*)&A[r * 256 + (c ^ (r & 7)) * 8];
#pragma unroll
        for (int in = 0; in < 2; ++in) {
            int nf = wn * 2 + in;
            bfrag b = *(const bfrag*)&Wp[(((nf * 8) + ks) * 64 + lane) * 8];
            acc[in] = __builtin_amdgcn_mfma_f32_16x16x32_bf16(a, b, acc[in],
                                                              0, 0, 0);
        }
    }

    // h3 -> LDS (alias A; all reads of A completed)
    __syncthreads();
    ushort* H = A;          // [BN rows][128 bf16], chunk swizzle c ^ (row&7)
#pragma unroll
    for (int in = 0; in < 2; ++in) {
        int ch = (wn * 2 + in) * 16 + lr;
        float bias = bl[ch];
        int cfull = ch >> 3, cb = ch & 7;
#pragma unroll
        for (int rq = 0; rq < 4; ++rq) {
            int row = wm * 16 + lg * 4 + rq;
            float v = acc[in][rq] + bias;
            v = (v > 0.f) ? v : 0.f;
            H[row * 128 + (cfull ^ (row & 7)) * 8 + cb] = f2bf(v);
        }
    }
    __syncthreads();

    // second GEMM + log_softmax: waves 0-1 (row-group = w)
    if (w < 2) {
        ffrag acc2[4];
#pragma unroll
        for (int in2 = 0; in2 < 4; ++in2) acc2[in2] = (ffrag)0.f;
#pragma unroll
        for (int ks = 0; ks < 4; ++ks) {
            int row = w * 16 + lr;
            int c2 = ks * 4 + lg;
            bfrag a2 = *(const bfrag*)&H[row * 128 + (c2 ^ (row & 7)) * 8];
#pragma unroll
            for (int in2 = 0; in2 < 4; ++in2) {
                bfrag b2 = *(const bfrag*)&Wpl[(((in2 * 4) + ks) * 64 + lane) * 8];
                acc2[in2] = __builtin_amdgcn_mfma_f32_16x16x32_bf16(
                    a2, b2, acc2[in2], 0, 0, 0);
            }
        }
        float bv0 = blin[lr], bv1 = blin[16 + lr], bv2 = blin[32 + lr],
              bv3 = blin[48 + lr];
#pragma unroll
        for (int rq = 0; rq < 4; ++rq) {
            int node = node0 + w * 16 + lg * 4 + rq;
            float L0 = acc2[0][rq] + bv0, L1 = acc2[1][rq] + bv1;
            float L2 = acc2[2][rq] + bv2, L3 = acc2[3][rq] + bv3;
            float m = fmaxf(fmaxf(L0, L1), fmaxf(L2, L3));
#pragma unroll
            for (int o = 1; o < 16; o <<= 1) m = fmaxf(m, __shfl_xor(m, o));
            float s = __expf(L0 - m) + __expf(L1 - m) + __expf(L2 - m) +
                      __expf(L3 - m);
#pragma unroll
            for (int o = 1; o < 16; o <<= 1) s += __shfl_xor(s, o);
            float ls = __logf(s) + m;
            if (node < N_NODES) {
                __builtin_nontemporal_store(L0 - ls, &out[node * OUTC + lr]);
                __builtin_nontemporal_store(L1 - ls, &out[node * OUTC + 16 + lr]);
                __builtin_nontemporal_store(L2 - ls, &out[node * OUTC + 32 + lr]);
                __builtin_nontemporal_store(L3 - ls, &out[node * OUTC + 48 + lr]);
            }
        }
    }
}

// ---------------------------------------------------------------------------

extern "C" void kernel_launch(void* const* d_in, const int* in_sizes, int n_in,
                              void* d_out, int out_size, void* d_ws,
                              size_t ws_size, hipStream_t stream) {
    const float* x = (const float*)d_in[0];
    const int* ei = (const int*)d_in[1];
    const int* src = ei;
    const int* dst = ei + N_EDGES;
    const float* Wl0 = (const float*)d_in[2];
    const float* bl0 = (const float*)d_in[3];
    const float* Wr0 = (const float*)d_in[4];
    const float* Wl1 = (const float*)d_in[5];
    const float* bl1 = (const float*)d_in[6];
    const float* Wr1 = (const float*)d_in[7];
    const float* Wl2 = (const float*)d_in[8];
    const float* bl2 = (const float*)d_in[9];
    const float* Wr2 = (const float*)d_in[10];
    const float* Wlin = (const float*)d_in[11];
    const float* blin = (const float*)d_in[12];

    // workspace layout (all 16B-aligned). h buffers ping-pong:
    //   L0: xb/xq -> bufA/bufAq ; L1: bufA/bufAq -> xb/xq (dead after L0) ;
    //   L2: xb/xq -> d_out.
    int* cnt = (int*)d_ws;                          // 50000 ints
    ushort* slots = (ushort*)(cnt + N_NODES);       // 3.2M ushorts (6.4 MB)
    uint* xb = (uint*)(slots + (size_t)N_NODES * CAP);  // 12.8 MB
    uint* bufA = xb + (size_t)N_NODES * 64;         // 12.8 MB
    uint* xq = bufA + (size_t)N_NODES * 64;         // 6.4 MB (fp8)
    uint* bufAq = xq + (size_t)N_NODES * 32;        // 6.4 MB (fp8)
    ushort* wp = (ushort*)(bufAq + (size_t)N_NODES * 32);  // 3*32768
    ushort* wpl = wp + 3 * 32768;                   // 8192

    hipMemsetAsync(cnt, 0, (size_t)N_NODES * sizeof(int), stream);

    k_prep_mega<<<FILLG_B + CAST_B + 3 * PREPW_B + WLIN_B, 256, 0, stream>>>(
        src, dst, cnt, slots, x, xb, xq,
        Wl0, Wr0, Wl1, Wr1, Wl2, Wr2, Wlin, wp, wpl);

    const int FGRID = (N_NODES + BN - 1) / BN;      // 1563

    k_sage_f<<<FGRID, 512, 0, stream>>>(xb, (const u32x2*)xq, cnt, slots,
                                        wp, bl0,
                                        (ushort*)bufA, (uchar*)bufAq);
    k_sage_f<<<FGRID, 512, 0, stream>>>(bufA, (const u32x2*)bufAq, cnt, slots,
                                        wp + 32768, bl1,
                                        (ushort*)xb, (uchar*)xq);
    k_sage_fout<<<FGRID, 512, 0, stream>>>(xb, (const u32x2*)xq, cnt, slots,
                                           wp + 65536, bl2, wpl, blin,
                                           (float*)d_out);
}

// Round 16
// 161.788 us; speedup vs baseline: 1.1551x; 1.1551x over previous
//
#include <hip/hip_runtime.h>
#include <math.h>

#define N_NODES 50000
#define N_EDGES 800000
#define C 128
#define OUTC 64
#define CAP 64               // padded-CSR slots/node; P(deg>64) ~ 3e-20/node
#define NSLICE 8             // XCD count; dst-slice per block-group (blk&7)
#define SLICE_N 6250         // 50000 / 8 exactly

#define FILL_CH 3125         // edge chunks: 800000 / 256 exactly
#define FILLG_B (FILL_CH * NSLICE)   // 25000 fill blocks (8 groups)
#define CAST_B 3125          // 50000*128/8 / 256 exactly
#define PREPW_B 128          // per layer, 3 layers
#define WLIN_B 32            // 128*64/256

#define BN 32                // nodes per fused block (32 rows, 8 waves)

typedef __attribute__((ext_vector_type(8))) short bfrag;   // 8 bf16 (4 VGPRs)
typedef __attribute__((ext_vector_type(4))) float ffrag;   // 4 fp32 acc
typedef __attribute__((ext_vector_type(2))) float f32x2;

__device__ __forceinline__ ushort f2bf(float f) {
    uint u = __builtin_bit_cast(uint, f);
    uint r = (u + 0x7FFFu + ((u >> 16) & 1u)) >> 16;       // RNE
    return (ushort)r;
}
__device__ __forceinline__ float bflo(uint v) {            // low bf16 of packed pair
    uint u = v << 16; return __builtin_bit_cast(float, u);
}
__device__ __forceinline__ float bfhi(uint v) {            // high bf16
    uint u = v & 0xFFFF0000u; return __builtin_bit_cast(float, u);
}
// fp8 e4m3 (HW-native, gfx950 OCP): pack 4 f32 -> 4 fp8 bytes in a uint
__device__ __forceinline__ uint pkfp8x4(float a, float b, float c, float d) {
    int w = __builtin_amdgcn_cvt_pk_fp8_f32(a, b, 0, false);
    w = __builtin_amdgcn_cvt_pk_fp8_f32(c, d, w, true);
    return (uint)w;
}
__device__ __forceinline__ uchar pkfp8(float v) {
    return (uchar)(__builtin_amdgcn_cvt_pk_fp8_f32(v, v, 0, false) & 0xFF);
}

// ---------------------------------------------------------------------------
// Mega prep kernel (r9 form; fill floor ~45 us measured across 4 designs —
// plain, ILP-4, two-pass bucket, XCD-sliced; r15's NT hints also regressed
// and are reverted: every "stream-once" buffer here is the next kernel's
// input, so NT forfeits warm-line reuse).
// Cast section emits BOTH bf16 (residual path) and fp8 (gather path).
// ---------------------------------------------------------------------------

__global__ __launch_bounds__(256) void k_prep_mega(
    const int* __restrict__ src, const int* __restrict__ dst,
    int* __restrict__ cnt, ushort* __restrict__ slots,
    const float4* __restrict__ x4, uint4* __restrict__ xb4,
    uint2* __restrict__ xq2,
    const float* __restrict__ Wl0, const float* __restrict__ Wr0,
    const float* __restrict__ Wl1, const float* __restrict__ Wr1,
    const float* __restrict__ Wl2, const float* __restrict__ Wr2,
    const float* __restrict__ Wlin,
    ushort* __restrict__ wp, ushort* __restrict__ wpl) {
    int blk = blockIdx.x;
    if (blk < FILLG_B) {
        int grp = blk & 7;                             // target dst slice / XCD
        int e = (blk >> 3) * 256 + threadIdx.x;        // < 800000 exactly
        int d = dst[e];
        if ((unsigned)(d - grp * SLICE_N) < (unsigned)SLICE_N) {
            int pos = atomicAdd(&cnt[d], 1);
            if (pos < CAP) slots[d * CAP + pos] = (ushort)src[e];
        }
    } else if (blk < FILLG_B + CAST_B) {
        int i = (blk - FILLG_B) * 256 + threadIdx.x;   // < 800000 exactly
        float4 a = x4[i * 2], b = x4[i * 2 + 1];
        uint4 o;
        o.x = (uint)f2bf(a.x) | ((uint)f2bf(a.y) << 16);
        o.y = (uint)f2bf(a.z) | ((uint)f2bf(a.w) << 16);
        o.z = (uint)f2bf(b.x) | ((uint)f2bf(b.y) << 16);
        o.w = (uint)f2bf(b.z) | ((uint)f2bf(b.w) << 16);
        xb4[i] = o;
        xq2[i] = make_uint2(pkfp8x4(a.x, a.y, a.z, a.w),
                            pkfp8x4(b.x, b.y, b.z, b.w));
    } else if (blk < FILLG_B + CAST_B + 3 * PREPW_B) {
        int sub = blk - (FILLG_B + CAST_B);
        int layer = sub >> 7;                          // /128
        const float *Wl, *Wr;
        if (layer == 0)      { Wl = Wl0; Wr = Wr0; }
        else if (layer == 1) { Wl = Wl1; Wr = Wr1; }
        else                 { Wl = Wl2; Wr = Wr2; }
        // wp[((nf*8 + ks)*64 + lane)*8 + j] = Wcat[k][n],
        //   n = nf*16 + (lane&15), k = ks*32 + (lane>>4)*8 + j
        int idx = (sub & 127) * 256 + threadIdx.x;     // 0..32767
        int j = idx & 7;
        int lane = (idx >> 3) & 63;
        int ks = (idx >> 9) & 7;
        int nf = idx >> 12;
        int n = nf * 16 + (lane & 15);
        int k = ks * 32 + (lane >> 4) * 8 + j;
        float v = (k < C) ? Wl[k * C + n] : Wr[(k - C) * C + n];
        wp[layer * 32768 + idx] = f2bf(v);
    } else {
        // Wlin pack: K=128 (4 ks), N=64 (4 nf); idx == ((nf*4+ks)*64+lane)*8+j
        int idx = (blk - (FILLG_B + CAST_B + 3 * PREPW_B)) * 256 + threadIdx.x;
        int j = idx & 7;
        int lane = (idx >> 3) & 63;
        int ks = (idx >> 9) & 3;
        int nf = idx >> 11;                            // 0..3
        int n = nf * 16 + (lane & 15);
        int k = ks * 32 + (lane >> 4) * 8 + j;
        wpl[idx] = f2bf(Wlin[k * OUTC + n]);
    }
}

// ---------------------------------------------------------------------------
// Gather stage v5: neighbor rows read from the fp8 shadow table hq (128B/row,
// uint2/lane) — halves the 8-XCD compulsory fetch vs bf16. Decode via HW
// v_cvt_pk_f32_fp8 (4 cvt + 8 fmaf per row-lane, cheaper than bf16 unpack).
// Own-h row still bf16 from hb (residual path accuracy). Serial-4 row form
// (r12's interleave spilled). 4 uint2 gathers in flight.
// ---------------------------------------------------------------------------

#define ACCQ(P, W, V) {                                                       \
    f32x2 p01 = __builtin_amdgcn_cvt_pk_f32_fp8((int)V.x, false);             \
    f32x2 p23 = __builtin_amdgcn_cvt_pk_f32_fp8((int)V.x, true);              \
    f32x2 p45 = __builtin_amdgcn_cvt_pk_f32_fp8((int)V.y, false);             \
    f32x2 p67 = __builtin_amdgcn_cvt_pk_f32_fp8((int)V.y, true);              \
    P##0 = fmaf(W, p01[0], P##0); P##1 = fmaf(W, p01[1], P##1);               \
    P##2 = fmaf(W, p23[0], P##2); P##3 = fmaf(W, p23[1], P##3);               \
    P##4 = fmaf(W, p45[0], P##4); P##5 = fmaf(W, p45[1], P##5);               \
    P##6 = fmaf(W, p67[0], P##6); P##7 = fmaf(W, p67[1], P##7); }

__device__ __forceinline__ void sage_gather_stage(
    ushort* A, const uint* __restrict__ hb, const uint2* __restrict__ hq,
    const int* __restrict__ cnt, const ushort* __restrict__ slots,
    int node0, int w, int lane) {
    const int grp = lane >> 4;
    const int slot = lane & 15;
    for (int rr = 0; rr < 4; ++rr) {
        int r = (w << 2) | rr;
        int node = node0 + r;
        int n = 0;
        uint4 hv = make_uint4(0u, 0u, 0u, 0u);
        if (node < N_NODES) {
            n = cnt[node];
            n = (n > CAP) ? CAP : n;
            if (grp == 0) hv = *(const uint4*)&hb[node * 64 + slot * 4];
        }
        float s0 = 0, s1 = 0, s2 = 0, s3 = 0, s4 = 0, s5 = 0, s6 = 0, s7 = 0;
        if (n > 0) {
            int sv = slots[node * CAP + ((lane < n) ? lane : 0)];
            for (int k = 0; k < n; k += 16) {
                int w0 = k + grp, w1 = k + 4 + grp;
                int w2 = k + 8 + grp, w3 = k + 12 + grp;
                int sA = __shfl(sv, w0), sB = __shfl(sv, w1);
                int sC = __shfl(sv, w2), sD = __shfl(sv, w3);
                float fA = (w0 < n) ? 1.f : 0.f;
                float fB = (w1 < n) ? 1.f : 0.f;
                float fC = (w2 < n) ? 1.f : 0.f;
                float fD = (w3 < n) ? 1.f : 0.f;
                // 4 independent 8B gathers in flight (fp8 row = 16 uint2)
                uint2 a = hq[sA * 16 + slot];
                uint2 b = hq[sB * 16 + slot];
                uint2 c = hq[sC * 16 + slot];
                uint2 d = hq[sD * 16 + slot];
                ACCQ(s, fA, a); ACCQ(s, fB, b);
                ACCQ(s, fC, c); ACCQ(s, fD, d);
            }
        }
#pragma unroll
        for (int o = 16; o <= 32; o <<= 1) {
            s0 += __shfl_xor(s0, o); s1 += __shfl_xor(s1, o);
            s2 += __shfl_xor(s2, o); s3 += __shfl_xor(s3, o);
            s4 += __shfl_xor(s4, o); s5 += __shfl_xor(s5, o);
            s6 += __shfl_xor(s6, o); s7 += __shfl_xor(s7, o);
        }
        if (grp == 0) {
            float rd = (n > 0) ? 1.0f / (float)n : 0.f;
            uint4 o4;
            o4.x = (uint)f2bf(s0 * rd) | ((uint)f2bf(s1 * rd) << 16);
            o4.y = (uint)f2bf(s2 * rd) | ((uint)f2bf(s3 * rd) << 16);
            o4.z = (uint)f2bf(s4 * rd) | ((uint)f2bf(s5 * rd) << 16);
            o4.w = (uint)f2bf(s6 * rd) | ((uint)f2bf(s7 * rd) << 16);
            // mean -> chunk slot; h -> chunk 16+slot (XOR row swizzle)
            *(uint4*)&A[r * 256 + (slot ^ (r & 7)) * 8] = o4;
            *(uint4*)&A[r * 256 + ((16 + slot) ^ (r & 7)) * 8] = hv;
        }
    }
}

// ---------------------------------------------------------------------------
// Fused SAGE layer: 512 threads = 8 waves, 32 nodes, 4 blocks/CU (r13).
// Epilogue dual-writes h as bf16 (out_b) + fp8 (out_q). outs must NOT alias
// the hb/hq being gathered this launch.
// ---------------------------------------------------------------------------

__global__ __launch_bounds__(512, 8) void k_sage_f(
    const uint* __restrict__ hb, const uint2* __restrict__ hq,
    const int* __restrict__ cnt, const ushort* __restrict__ slots,
    const ushort* __restrict__ Wp, const float* __restrict__ bl,
    ushort* __restrict__ out_b, uchar* __restrict__ out_q) {
    __shared__ __align__(16) ushort A[BN * 256];
    const int t = threadIdx.x;
    const int w = t >> 6, lane = t & 63;
    const int node0 = blockIdx.x * BN;

    sage_gather_stage(A, hb, hq, cnt, slots, node0, w, lane);
    __syncthreads();

    const int wm = w >> 2, wn = w & 3;
    const int lg = lane >> 4, lr = lane & 15;
    ffrag acc[2];
    acc[0] = (ffrag)0.f;
    acc[1] = (ffrag)0.f;
#pragma unroll 2
    for (int ks = 0; ks < 8; ++ks) {
        int r = wm * 16 + lr;
        int c = ks * 4 + lg;
        bfrag a = *(const bfrag*)&A[r * 256 + (c ^ (r & 7)) * 8];
#pragma unroll
        for (int in = 0; in < 2; ++in) {
            int nf = wn * 2 + in;
            bfrag b = *(const bfrag*)&Wp[(((nf * 8) + ks) * 64 + lane) * 8];
            acc[in] = __builtin_amdgcn_mfma_f32_16x16x32_bf16(a, b, acc[in],
                                                              0, 0, 0);
        }
    }
#pragma unroll
    for (int in = 0; in < 2; ++in) {
        int ch = (wn * 2 + in) * 16 + lr;
        float bias = bl[ch];
#pragma unroll
        for (int rq = 0; rq < 4; ++rq) {
            int node = node0 + wm * 16 + lg * 4 + rq;
            if (node < N_NODES) {
                float v = acc[in][rq] + bias;
                v = (v > 0.f) ? v : 0.f;
                out_b[node * C + ch] = f2bf(v);
                out_q[node * C + ch] = pkfp8(v);
            }
        }
    }
}

// ---------------------------------------------------------------------------
// Fused last layer: gather + GEMM + final projection + log_softmax.
// Second GEMM + softmax on waves 0-1 (rows w*16..+15 each). No h output.
// ---------------------------------------------------------------------------

__global__ __launch_bounds__(512, 8) void k_sage_fout(
    const uint* __restrict__ hb, const uint2* __restrict__ hq,
    const int* __restrict__ cnt, const ushort* __restrict__ slots,
    const ushort* __restrict__ Wp, const float* __restrict__ bl,
    const ushort* __restrict__ Wpl, const float* __restrict__ blin,
    float* __restrict__ out) {
    __shared__ __align__(16) ushort A[BN * 256];
    const int t = threadIdx.x;
    const int w = t >> 6, lane = t & 63;
    const int node0 = blockIdx.x * BN;

    sage_gather_stage(A, hb, hq, cnt, slots, node0, w, lane);
    __syncthreads();

    const int wm = w >> 2, wn = w & 3;
    const int lg = lane >> 4, lr = lane & 15;
    ffrag acc[2];
    acc[0] = (ffrag)0.f;
    acc[1] = (ffrag)0.f;
#pragma unroll 2
    for (int ks = 0; ks < 8; ++ks) {
        int r = wm * 16 + lr;
        int c = ks * 4 + lg;
        bfrag a = *(const bfrag*)&A[r * 256 + (c ^ (r & 7)) * 8];
#pragma unroll
        for (int in = 0; in < 2; ++in) {
            int nf = wn * 2 + in;
            bfrag b = *(const bfrag*)&Wp[(((nf * 8) + ks) * 64 + lane) * 8];
            acc[in] = __builtin_amdgcn_mfma_f32_16x16x32_bf16(a, b, acc[in],
                                                              0, 0, 0);
        }
    }

    // h3 -> LDS (alias A; all reads of A completed)
    __syncthreads();
    ushort* H = A;          // [BN rows][128 bf16], chunk swizzle c ^ (row&7)
#pragma unroll
    for (int in = 0; in < 2; ++in) {
        int ch = (wn * 2 + in) * 16 + lr;
        float bias = bl[ch];
        int cfull = ch >> 3, cb = ch & 7;
#pragma unroll
        for (int rq = 0; rq < 4; ++rq) {
            int row = wm * 16 + lg * 4 + rq;
            float v = acc[in][rq] + bias;
            v = (v > 0.f) ? v : 0.f;
            H[row * 128 + (cfull ^ (row & 7)) * 8 + cb] = f2bf(v);
        }
    }
    __syncthreads();

    // second GEMM + log_softmax: waves 0-1 (row-group = w)
    if (w < 2) {
        ffrag acc2[4];
#pragma unroll
        for (int in2 = 0; in2 < 4; ++in2) acc2[in2] = (ffrag)0.f;
#pragma unroll
        for (int ks = 0; ks < 4; ++ks) {
            int row = w * 16 + lr;
            int c2 = ks * 4 + lg;
            bfrag a2 = *(const bfrag*)&H[row * 128 + (c2 ^ (row & 7)) * 8];
#pragma unroll
            for (int in2 = 0; in2 < 4; ++in2) {
                bfrag b2 = *(const bfrag*)&Wpl[(((in2 * 4) + ks) * 64 + lane) * 8];
                acc2[in2] = __builtin_amdgcn_mfma_f32_16x16x32_bf16(
                    a2, b2, acc2[in2], 0, 0, 0);
            }
        }
        float bv0 = blin[lr], bv1 = blin[16 + lr], bv2 = blin[32 + lr],
              bv3 = blin[48 + lr];
#pragma unroll
        for (int rq = 0; rq < 4; ++rq) {
            int node = node0 + w * 16 + lg * 4 + rq;
            float L0 = acc2[0][rq] + bv0, L1 = acc2[1][rq] + bv1;
            float L2 = acc2[2][rq] + bv2, L3 = acc2[3][rq] + bv3;
            float m = fmaxf(fmaxf(L0, L1), fmaxf(L2, L3));
#pragma unroll
            for (int o = 1; o < 16; o <<= 1) m = fmaxf(m, __shfl_xor(m, o));
            float s = __expf(L0 - m) + __expf(L1 - m) + __expf(L2 - m) +
                      __expf(L3 - m);
#pragma unroll
            for (int o = 1; o < 16; o <<= 1) s += __shfl_xor(s, o);
            float ls = __logf(s) + m;
            if (node < N_NODES) {
                out[node * OUTC + lr]      = L0 - ls;
                out[node * OUTC + 16 + lr] = L1 - ls;
                out[node * OUTC + 32 + lr] = L2 - ls;
                out[node * OUTC + 48 + lr] = L3 - ls;
            }
        }
    }
}

// ---------------------------------------------------------------------------

extern "C" void kernel_launch(void* const* d_in, const int* in_sizes, int n_in,
                              void* d_out, int out_size, void* d_ws,
                              size_t ws_size, hipStream_t stream) {
    const float* x = (const float*)d_in[0];
    const int* ei = (const int*)d_in[1];
    const int* src = ei;
    const int* dst = ei + N_EDGES;
    const float* Wl0 = (const float*)d_in[2];
    const float* bl0 = (const float*)d_in[3];
    const float* Wr0 = (const float*)d_in[4];
    const float* Wl1 = (const float*)d_in[5];
    const float* bl1 = (const float*)d_in[6];
    const float* Wr1 = (const float*)d_in[7];
    const float* Wl2 = (const float*)d_in[8];
    const float* bl2 = (const float*)d_in[9];
    const float* Wr2 = (const float*)d_in[10];
    const float* Wlin = (const float*)d_in[11];
    const float* blin = (const float*)d_in[12];

    // workspace layout (all 16B-aligned). h buffers ping-pong:
    //   L0: xb/xq -> bufA/bufAq ; L1: bufA/bufAq -> xb/xq (dead after L0) ;
    //   L2: xb/xq -> d_out. Keeps total at ~45 MB (r9-proven envelope).
    int* cnt = (int*)d_ws;                          // 50000 ints
    ushort* slots = (ushort*)(cnt + N_NODES);       // 3.2M ushorts (6.4 MB)
    uint* xb = (uint*)(slots + (size_t)N_NODES * CAP);  // 12.8 MB
    uint* bufA = xb + (size_t)N_NODES * 64;         // 12.8 MB
    uint* xq = bufA + (size_t)N_NODES * 64;         // 6.4 MB (fp8)
    uint* bufAq = xq + (size_t)N_NODES * 32;        // 6.4 MB (fp8)
    ushort* wp = (ushort*)(bufAq + (size_t)N_NODES * 32);  // 3*32768
    ushort* wpl = wp + 3 * 32768;                   // 8192

    hipMemsetAsync(cnt, 0, (size_t)N_NODES * sizeof(int), stream);

    k_prep_mega<<<FILLG_B + CAST_B + 3 * PREPW_B + WLIN_B, 256, 0, stream>>>(
        src, dst, cnt, slots, (const float4*)x, (uint4*)xb, (uint2*)xq,
        Wl0, Wr0, Wl1, Wr1, Wl2, Wr2, Wlin, wp, wpl);

    const int FGRID = (N_NODES + BN - 1) / BN;      // 1563

    k_sage_f<<<FGRID, 512, 0, stream>>>(xb, (const uint2*)xq, cnt, slots,
                                        wp, bl0,
                                        (ushort*)bufA, (uchar*)bufAq);
    k_sage_f<<<FGRID, 512, 0, stream>>>(bufA, (const uint2*)bufAq, cnt, slots,
                                        wp + 32768, bl1,
                                        (ushort*)xb, (uchar*)xq);
    k_sage_fout<<<FGRID, 512, 0, stream>>>(xb, (const uint2*)xq, cnt, slots,
                                           wp + 65536, bl2, wpl, blin,
                                           (float*)d_out);
}

// Round 17
// 159.217 us; speedup vs baseline: 1.1738x; 1.0161x over previous
//
#include <hip/hip_runtime.h>
#include <math.h>

#define N_NODES 50000
#define N_EDGES 800000
#define C 128
#define OUTC 64
#define CAP 64               // padded-CSR slots/node; P(deg>64) ~ 3e-20/node
#define NSLICE 8             // XCD count; dst-slice per block-group (blk&7)
#define SLICE_N 6250         // 50000 / 8 exactly

#define FILL_CH 3125         // edge chunks: 800000 / 256 exactly
#define FILLG_B (FILL_CH * NSLICE)   // 25000 fill blocks (8 groups)
#define CAST_B 3125          // 50000*128/8 / 256 exactly
#define PREPW_B 128          // per layer, 3 layers
#define WLIN_B 32            // 128*64/256

#define BN 16                // nodes per fused block (16 rows, 4 waves) — r17:
                             // 8 blocks/CU for max gather phase-diversity

typedef __attribute__((ext_vector_type(8))) short bfrag;   // 8 bf16 (4 VGPRs)
typedef __attribute__((ext_vector_type(4))) float ffrag;   // 4 fp32 acc
typedef __attribute__((ext_vector_type(2))) float f32x2;

__device__ __forceinline__ ushort f2bf(float f) {
    uint u = __builtin_bit_cast(uint, f);
    uint r = (u + 0x7FFFu + ((u >> 16) & 1u)) >> 16;       // RNE
    return (ushort)r;
}
__device__ __forceinline__ float bflo(uint v) {            // low bf16 of packed pair
    uint u = v << 16; return __builtin_bit_cast(float, u);
}
__device__ __forceinline__ float bfhi(uint v) {            // high bf16
    uint u = v & 0xFFFF0000u; return __builtin_bit_cast(float, u);
}
// fp8 e4m3 (HW-native, gfx950 OCP): pack 4 f32 -> 4 fp8 bytes in a uint
__device__ __forceinline__ uint pkfp8x4(float a, float b, float c, float d) {
    int w = __builtin_amdgcn_cvt_pk_fp8_f32(a, b, 0, false);
    w = __builtin_amdgcn_cvt_pk_fp8_f32(c, d, w, true);
    return (uint)w;
}
__device__ __forceinline__ uchar pkfp8(float v) {
    return (uchar)(__builtin_amdgcn_cvt_pk_fp8_f32(v, v, 0, false) & 0xFF);
}

// ---------------------------------------------------------------------------
// Mega prep kernel (r9 form; fill floor ~45 us measured across 4 designs;
// r15 NT-hint variant regressed and is reverted).
// Cast section emits BOTH bf16 (residual path) and fp8 (gather path).
// ---------------------------------------------------------------------------

__global__ __launch_bounds__(256) void k_prep_mega(
    const int* __restrict__ src, const int* __restrict__ dst,
    int* __restrict__ cnt, ushort* __restrict__ slots,
    const float4* __restrict__ x4, uint4* __restrict__ xb4,
    uint2* __restrict__ xq2,
    const float* __restrict__ Wl0, const float* __restrict__ Wr0,
    const float* __restrict__ Wl1, const float* __restrict__ Wr1,
    const float* __restrict__ Wl2, const float* __restrict__ Wr2,
    const float* __restrict__ Wlin,
    ushort* __restrict__ wp, ushort* __restrict__ wpl) {
    int blk = blockIdx.x;
    if (blk < FILLG_B) {
        int grp = blk & 7;                             // target dst slice / XCD
        int e = (blk >> 3) * 256 + threadIdx.x;        // < 800000 exactly
        int d = dst[e];
        if ((unsigned)(d - grp * SLICE_N) < (unsigned)SLICE_N) {
            int pos = atomicAdd(&cnt[d], 1);
            if (pos < CAP) slots[d * CAP + pos] = (ushort)src[e];
        }
    } else if (blk < FILLG_B + CAST_B) {
        int i = (blk - FILLG_B) * 256 + threadIdx.x;   // < 800000 exactly
        float4 a = x4[i * 2], b = x4[i * 2 + 1];
        uint4 o;
        o.x = (uint)f2bf(a.x) | ((uint)f2bf(a.y) << 16);
        o.y = (uint)f2bf(a.z) | ((uint)f2bf(a.w) << 16);
        o.z = (uint)f2bf(b.x) | ((uint)f2bf(b.y) << 16);
        o.w = (uint)f2bf(b.z) | ((uint)f2bf(b.w) << 16);
        xb4[i] = o;
        xq2[i] = make_uint2(pkfp8x4(a.x, a.y, a.z, a.w),
                            pkfp8x4(b.x, b.y, b.z, b.w));
    } else if (blk < FILLG_B + CAST_B + 3 * PREPW_B) {
        int sub = blk - (FILLG_B + CAST_B);
        int layer = sub >> 7;                          // /128
        const float *Wl, *Wr;
        if (layer == 0)      { Wl = Wl0; Wr = Wr0; }
        else if (layer == 1) { Wl = Wl1; Wr = Wr1; }
        else                 { Wl = Wl2; Wr = Wr2; }
        // wp[((nf*8 + ks)*64 + lane)*8 + j] = Wcat[k][n],
        //   n = nf*16 + (lane&15), k = ks*32 + (lane>>4)*8 + j
        int idx = (sub & 127) * 256 + threadIdx.x;     // 0..32767
        int j = idx & 7;
        int lane = (idx >> 3) & 63;
        int ks = (idx >> 9) & 7;
        int nf = idx >> 12;
        int n = nf * 16 + (lane & 15);
        int k = ks * 32 + (lane >> 4) * 8 + j;
        float v = (k < C) ? Wl[k * C + n] : Wr[(k - C) * C + n];
        wp[layer * 32768 + idx] = f2bf(v);
    } else {
        // Wlin pack: K=128 (4 ks), N=64 (4 nf); idx == ((nf*4+ks)*64+lane)*8+j
        int idx = (blk - (FILLG_B + CAST_B + 3 * PREPW_B)) * 256 + threadIdx.x;
        int j = idx & 7;
        int lane = (idx >> 3) & 63;
        int ks = (idx >> 9) & 3;
        int nf = idx >> 11;                            // 0..3
        int n = nf * 16 + (lane & 15);
        int k = ks * 32 + (lane >> 4) * 8 + j;
        wpl[idx] = f2bf(Wlin[k * OUTC + n]);
    }
}

// ---------------------------------------------------------------------------
// Gather stage (fp8 table, r14-proven, serial-4 rows/wave, 4 uint2 gathers
// in flight, fits 64 VGPRs). With BN=16 and 4 waves, w in 0..3 -> rows 0..15.
// ---------------------------------------------------------------------------

#define ACCQ(P, W, V) {                                                       \
    f32x2 p01 = __builtin_amdgcn_cvt_pk_f32_fp8((int)V.x, false);             \
    f32x2 p23 = __builtin_amdgcn_cvt_pk_f32_fp8((int)V.x, true);              \
    f32x2 p45 = __builtin_amdgcn_cvt_pk_f32_fp8((int)V.y, false);             \
    f32x2 p67 = __builtin_amdgcn_cvt_pk_f32_fp8((int)V.y, true);              \
    P##0 = fmaf(W, p01[0], P##0); P##1 = fmaf(W, p01[1], P##1);               \
    P##2 = fmaf(W, p23[0], P##2); P##3 = fmaf(W, p23[1], P##3);               \
    P##4 = fmaf(W, p45[0], P##4); P##5 = fmaf(W, p45[1], P##5);               \
    P##6 = fmaf(W, p67[0], P##6); P##7 = fmaf(W, p67[1], P##7); }

__device__ __forceinline__ void sage_gather_stage(
    ushort* A, const uint* __restrict__ hb, const uint2* __restrict__ hq,
    const int* __restrict__ cnt, const ushort* __restrict__ slots,
    int node0, int w, int lane) {
    const int grp = lane >> 4;
    const int slot = lane & 15;
    for (int rr = 0; rr < 4; ++rr) {
        int r = (w << 2) | rr;
        int node = node0 + r;
        int n = 0;
        uint4 hv = make_uint4(0u, 0u, 0u, 0u);
        if (node < N_NODES) {
            n = cnt[node];
            n = (n > CAP) ? CAP : n;
            if (grp == 0) hv = *(const uint4*)&hb[node * 64 + slot * 4];
        }
        float s0 = 0, s1 = 0, s2 = 0, s3 = 0, s4 = 0, s5 = 0, s6 = 0, s7 = 0;
        if (n > 0) {
            int sv = slots[node * CAP + ((lane < n) ? lane : 0)];
            for (int k = 0; k < n; k += 16) {
                int w0 = k + grp, w1 = k + 4 + grp;
                int w2 = k + 8 + grp, w3 = k + 12 + grp;
                int sA = __shfl(sv, w0), sB = __shfl(sv, w1);
                int sC = __shfl(sv, w2), sD = __shfl(sv, w3);
                float fA = (w0 < n) ? 1.f : 0.f;
                float fB = (w1 < n) ? 1.f : 0.f;
                float fC = (w2 < n) ? 1.f : 0.f;
                float fD = (w3 < n) ? 1.f : 0.f;
                // 4 independent 8B gathers in flight (fp8 row = 16 uint2)
                uint2 a = hq[sA * 16 + slot];
                uint2 b = hq[sB * 16 + slot];
                uint2 c = hq[sC * 16 + slot];
                uint2 d = hq[sD * 16 + slot];
                ACCQ(s, fA, a); ACCQ(s, fB, b);
                ACCQ(s, fC, c); ACCQ(s, fD, d);
            }
        }
#pragma unroll
        for (int o = 16; o <= 32; o <<= 1) {
            s0 += __shfl_xor(s0, o); s1 += __shfl_xor(s1, o);
            s2 += __shfl_xor(s2, o); s3 += __shfl_xor(s3, o);
            s4 += __shfl_xor(s4, o); s5 += __shfl_xor(s5, o);
            s6 += __shfl_xor(s6, o); s7 += __shfl_xor(s7, o);
        }
        if (grp == 0) {
            float rd = (n > 0) ? 1.0f / (float)n : 0.f;
            uint4 o4;
            o4.x = (uint)f2bf(s0 * rd) | ((uint)f2bf(s1 * rd) << 16);
            o4.y = (uint)f2bf(s2 * rd) | ((uint)f2bf(s3 * rd) << 16);
            o4.z = (uint)f2bf(s4 * rd) | ((uint)f2bf(s5 * rd) << 16);
            o4.w = (uint)f2bf(s6 * rd) | ((uint)f2bf(s7 * rd) << 16);
            // mean -> chunk slot; h -> chunk 16+slot (XOR row swizzle)
            *(uint4*)&A[r * 256 + (slot ^ (r & 7)) * 8] = o4;
            *(uint4*)&A[r * 256 + ((16 + slot) ^ (r & 7)) * 8] = hv;
        }
    }
}

// ---------------------------------------------------------------------------
// Fused SAGE layer v5: 256 threads = 4 waves, 16 nodes, 8 blocks/CU
// (launch_bounds(256,8): 8 waves/EU = 32 waves/CU = 8 x 4-wave blocks).
// 8 independent block phases/CU -> ~7/8 of resident waves in gather phase.
// MFMA: wave w -> ALL 16 rows, ch w*32..+31 (2 frags, 8 ks). Per-wave MFMA
// count unchanged vs r13 (16). Epilogue dual-writes bf16 + fp8.
// out must NOT alias the hb/hq being gathered this launch.
// ---------------------------------------------------------------------------

__global__ __launch_bounds__(256, 8) void k_sage_f(
    const uint* __restrict__ hb, const uint2* __restrict__ hq,
    const int* __restrict__ cnt, const ushort* __restrict__ slots,
    const ushort* __restrict__ Wp, const float* __restrict__ bl,
    ushort* __restrict__ out_b, uchar* __restrict__ out_q) {
    __shared__ __align__(16) ushort A[BN * 256];   // 8 KB
    const int t = threadIdx.x;
    const int w = t >> 6, lane = t & 63;
    const int node0 = blockIdx.x * BN;

    sage_gather_stage(A, hb, hq, cnt, slots, node0, w, lane);
    __syncthreads();

    const int lg = lane >> 4, lr = lane & 15;
    ffrag acc[2];
    acc[0] = (ffrag)0.f;
    acc[1] = (ffrag)0.f;
#pragma unroll 2
    for (int ks = 0; ks < 8; ++ks) {
        int r = lr;                                  // 16 rows, all waves
        int c = ks * 4 + lg;
        bfrag a = *(const bfrag*)&A[r * 256 + (c ^ (r & 7)) * 8];
#pragma unroll
        for (int in = 0; in < 2; ++in) {
            int nf = w * 2 + in;                     // ch block 0..7
            bfrag b = *(const bfrag*)&Wp[(((nf * 8) + ks) * 64 + lane) * 8];
            acc[in] = __builtin_amdgcn_mfma_f32_16x16x32_bf16(a, b, acc[in],
                                                              0, 0, 0);
        }
    }
#pragma unroll
    for (int in = 0; in < 2; ++in) {
        int ch = (w * 2 + in) * 16 + lr;
        float bias = bl[ch];
#pragma unroll
        for (int rq = 0; rq < 4; ++rq) {
            int node = node0 + lg * 4 + rq;
            if (node < N_NODES) {
                float v = acc[in][rq] + bias;
                v = (v > 0.f) ? v : 0.f;
                out_b[node * C + ch] = f2bf(v);
                out_q[node * C + ch] = pkfp8(v);
            }
        }
    }
}

// ---------------------------------------------------------------------------
// Fused last layer: gather + GEMM + final projection + log_softmax.
// Second GEMM + softmax on wave 0 (16 rows). No h output.
// ---------------------------------------------------------------------------

__global__ __launch_bounds__(256, 8) void k_sage_fout(
    const uint* __restrict__ hb, const uint2* __restrict__ hq,
    const int* __restrict__ cnt, const ushort* __restrict__ slots,
    const ushort* __restrict__ Wp, const float* __restrict__ bl,
    const ushort* __restrict__ Wpl, const float* __restrict__ blin,
    float* __restrict__ out) {
    __shared__ __align__(16) ushort A[BN * 256];
    const int t = threadIdx.x;
    const int w = t >> 6, lane = t & 63;
    const int node0 = blockIdx.x * BN;

    sage_gather_stage(A, hb, hq, cnt, slots, node0, w, lane);
    __syncthreads();

    const int lg = lane >> 4, lr = lane & 15;
    ffrag acc[2];
    acc[0] = (ffrag)0.f;
    acc[1] = (ffrag)0.f;
#pragma unroll 2
    for (int ks = 0; ks < 8; ++ks) {
        int r = lr;
        int c = ks * 4 + lg;
        bfrag a = *(const bfrag*)&A[r * 256 + (c ^ (r & 7)) * 8];
#pragma unroll
        for (int in = 0; in < 2; ++in) {
            int nf = w * 2 + in;
            bfrag b = *(const bfrag*)&Wp[(((nf * 8) + ks) * 64 + lane) * 8];
            acc[in] = __builtin_amdgcn_mfma_f32_16x16x32_bf16(a, b, acc[in],
                                                              0, 0, 0);
        }
    }

    // h3 -> LDS (alias A; all reads of A completed)
    __syncthreads();
    ushort* H = A;          // [16 rows][128 bf16], chunk swizzle c ^ (row&7)
#pragma unroll
    for (int in = 0; in < 2; ++in) {
        int ch = (w * 2 + in) * 16 + lr;
        float bias = bl[ch];
        int cfull = ch >> 3, cb = ch & 7;
#pragma unroll
        for (int rq = 0; rq < 4; ++rq) {
            int row = lg * 4 + rq;
            float v = acc[in][rq] + bias;
            v = (v > 0.f) ? v : 0.f;
            H[row * 128 + (cfull ^ (row & 7)) * 8 + cb] = f2bf(v);
        }
    }
    __syncthreads();

    // second GEMM + log_softmax: wave 0 only (16 rows)
    if (w == 0) {
        ffrag acc2[4];
#pragma unroll
        for (int in2 = 0; in2 < 4; ++in2) acc2[in2] = (ffrag)0.f;
#pragma unroll
        for (int ks = 0; ks < 4; ++ks) {
            int row = lr;
            int c2 = ks * 4 + lg;
            bfrag a2 = *(const bfrag*)&H[row * 128 + (c2 ^ (row & 7)) * 8];
#pragma unroll
            for (int in2 = 0; in2 < 4; ++in2) {
                bfrag b2 = *(const bfrag*)&Wpl[(((in2 * 4) + ks) * 64 + lane) * 8];
                acc2[in2] = __builtin_amdgcn_mfma_f32_16x16x32_bf16(
                    a2, b2, acc2[in2], 0, 0, 0);
            }
        }
        float bv0 = blin[lr], bv1 = blin[16 + lr], bv2 = blin[32 + lr],
              bv3 = blin[48 + lr];
#pragma unroll
        for (int rq = 0; rq < 4; ++rq) {
            int node = node0 + lg * 4 + rq;
            float L0 = acc2[0][rq] + bv0, L1 = acc2[1][rq] + bv1;
            float L2 = acc2[2][rq] + bv2, L3 = acc2[3][rq] + bv3;
            float m = fmaxf(fmaxf(L0, L1), fmaxf(L2, L3));
#pragma unroll
            for (int o = 1; o < 16; o <<= 1) m = fmaxf(m, __shfl_xor(m, o));
            float s = __expf(L0 - m) + __expf(L1 - m) + __expf(L2 - m) +
                      __expf(L3 - m);
#pragma unroll
            for (int o = 1; o < 16; o <<= 1) s += __shfl_xor(s, o);
            float ls = __logf(s) + m;
            if (node < N_NODES) {
                out[node * OUTC + lr]      = L0 - ls;
                out[node * OUTC + 16 + lr] = L1 - ls;
                out[node * OUTC + 32 + lr] = L2 - ls;
                out[node * OUTC + 48 + lr] = L3 - ls;
            }
        }
    }
}

// ---------------------------------------------------------------------------

extern "C" void kernel_launch(void* const* d_in, const int* in_sizes, int n_in,
                              void* d_out, int out_size, void* d_ws,
                              size_t ws_size, hipStream_t stream) {
    const float* x = (const float*)d_in[0];
    const int* ei = (const int*)d_in[1];
    const int* src = ei;
    const int* dst = ei + N_EDGES;
    const float* Wl0 = (const float*)d_in[2];
    const float* bl0 = (const float*)d_in[3];
    const float* Wr0 = (const float*)d_in[4];
    const float* Wl1 = (const float*)d_in[5];
    const float* bl1 = (const float*)d_in[6];
    const float* Wr1 = (const float*)d_in[7];
    const float* Wl2 = (const float*)d_in[8];
    const float* bl2 = (const float*)d_in[9];
    const float* Wr2 = (const float*)d_in[10];
    const float* Wlin = (const float*)d_in[11];
    const float* blin = (const float*)d_in[12];

    // workspace layout (all 16B-aligned). h buffers ping-pong:
    //   L0: xb/xq -> bufA/bufAq ; L1: bufA/bufAq -> xb/xq (dead after L0) ;
    //   L2: xb/xq -> d_out.
    int* cnt = (int*)d_ws;                          // 50000 ints
    ushort* slots = (ushort*)(cnt + N_NODES);       // 3.2M ushorts (6.4 MB)
    uint* xb = (uint*)(slots + (size_t)N_NODES * CAP);  // 12.8 MB
    uint* bufA = xb + (size_t)N_NODES * 64;         // 12.8 MB
    uint* xq = bufA + (size_t)N_NODES * 64;         // 6.4 MB (fp8)
    uint* bufAq = xq + (size_t)N_NODES * 32;        // 6.4 MB (fp8)
    ushort* wp = (ushort*)(bufAq + (size_t)N_NODES * 32);  // 3*32768
    ushort* wpl = wp + 3 * 32768;                   // 8192

    hipMemsetAsync(cnt, 0, (size_t)N_NODES * sizeof(int), stream);

    k_prep_mega<<<FILLG_B + CAST_B + 3 * PREPW_B + WLIN_B, 256, 0, stream>>>(
        src, dst, cnt, slots, (const float4*)x, (uint4*)xb, (uint2*)xq,
        Wl0, Wr0, Wl1, Wr1, Wl2, Wr2, Wlin, wp, wpl);

    const int FGRID = (N_NODES + BN - 1) / BN;      // 3125

    k_sage_f<<<FGRID, 256, 0, stream>>>(xb, (const uint2*)xq, cnt, slots,
                                        wp, bl0,
                                        (ushort*)bufA, (uchar*)bufAq);
    k_sage_f<<<FGRID, 256, 0, stream>>>(bufA, (const uint2*)bufAq, cnt, slots,
                                        wp + 32768, bl1,
                                        (ushort*)xb, (uchar*)xq);
    k_sage_fout<<<FGRID, 256, 0, stream>>>(xb, (const uint2*)xq, cnt, slots,
                                           wp + 65536, bl2, wpl, blin,
                                           (float*)d_out);
}